// Round 5
// baseline (901.551 us; speedup 1.0000x reference)
//
#include <hip/hip_runtime.h>

#define S_DIM 1024
#define INNER 32
#define PAIR  128
#define LSEQ  1024

typedef float f4 __attribute__((ext_vector_type(4)));

// ---------------------------------------------------------------------------
// Kernel 1: per-row LayerNorm + projection to 64 (q|k), plus the separable
// "diff" term precomputation: Aq = q @ W2, Ak = k @ W2  (W2 = o_w[32:64,:]).
// One block per sequence row. 256 threads.  (~10 us total; not the target.)
// ---------------------------------------------------------------------------
__global__ __launch_bounds__(256) void ln_proj_kernel(
    const float* __restrict__ x,      // (1024, 1024)
    const float* __restrict__ gamma,  // (1024)
    const float* __restrict__ beta,   // (1024)
    const float* __restrict__ pw,     // (1024, 64)
    const float* __restrict__ pb,     // (64)
    const float* __restrict__ ow,     // (64, 128)
    float* __restrict__ qk,           // (1024, 64)  q=cols 0..31, k=cols 32..63
    float* __restrict__ Aq,           // (1024, 128)
    float* __restrict__ Ak)           // (1024, 128)
{
    const int row  = blockIdx.x;
    const int t    = threadIdx.x;
    const int lane = t & 63;
    const int wv   = t >> 6;

    __shared__ float s_sh[S_DIM];
    __shared__ float wsum[4], wsum2[4];
    __shared__ float hpart[4][64];
    __shared__ float h_sh[64];

    // --- load 4 elements per thread, accumulate sums ---
    float4 xv = ((const float4*)(x + (size_t)row * S_DIM))[t];
    float sum = xv.x + xv.y + xv.z + xv.w;
    float sq  = xv.x*xv.x + xv.y*xv.y + xv.z*xv.z + xv.w*xv.w;
    #pragma unroll
    for (int off = 32; off; off >>= 1) {
        sum += __shfl_down(sum, off, 64);
        sq  += __shfl_down(sq,  off, 64);
    }
    if (lane == 0) { wsum[wv] = sum; wsum2[wv] = sq; }
    __syncthreads();
    float tot  = wsum[0] + wsum[1] + wsum[2] + wsum[3];
    float tot2 = wsum2[0] + wsum2[1] + wsum2[2] + wsum2[3];
    float mu   = tot * (1.0f / S_DIM);
    float var  = tot2 * (1.0f / S_DIM) - mu * mu;
    float rstd = rsqrtf(var + 1e-5f);

    float4 gv = ((const float4*)gamma)[t];
    float4 bv = ((const float4*)beta)[t];
    float4 sv;
    sv.x = (xv.x - mu) * rstd * gv.x + bv.x;
    sv.y = (xv.y - mu) * rstd * gv.y + bv.y;
    sv.z = (xv.z - mu) * rstd * gv.z + bv.z;
    sv.w = (xv.w - mu) * rstd * gv.w + bv.w;
    ((float4*)s_sh)[t] = sv;
    __syncthreads();

    // --- projection: h[c] = sum_d s[d] * pw[d,c] ; split d over 4 waves ---
    {
        const int c    = lane;     // 0..63 output column
        const int part = wv;       // 0..3
        const int dbase = part * 256;
        const float* pwp = pw + c;
        float acc = 0.f;
        #pragma unroll 8
        for (int d = 0; d < 256; ++d) {
            acc = fmaf(s_sh[dbase + d], pwp[(size_t)(dbase + d) * 64], acc);
        }
        hpart[part][c] = acc;
    }
    __syncthreads();
    if (t < 64) {
        float h = hpart[0][t] + hpart[1][t] + hpart[2][t] + hpart[3][t] + pb[t];
        h_sh[t] = h;
        qk[(size_t)row * 64 + t] = h;
    }
    __syncthreads();

    // --- Aq[row,p] = sum_{c<32} q[c]*W2[c,p] ;  Ak likewise with k ---
    {
        const int p    = t & 127;
        const int half = t >> 7;              // 0 -> Aq, 1 -> Ak
        const float* w2 = ow + 32 * PAIR + p; // W2 base
        const float* hh = h_sh + half * 32;
        float acc = 0.f;
        #pragma unroll
        for (int c = 0; c < 32; ++c)
            acc = fmaf(hh[c], w2[(size_t)c * PAIR], acc);
        if (half == 0) Aq[(size_t)row * PAIR + p] = acc;
        else           Ak[(size_t)row * PAIR + p] = acc;
    }
}

// ---------------------------------------------------------------------------
// Kernel 2: out[i,j,p] = sum_{c<32} q[j,c]*k[i,c]*W1[c,p] + Aq[j,p] - Ak[i,p]
//                        + o_b[p]
// Grid: (1024 i, 8 jblk). Block: 256 threads = 4 waves; wave owns 32 j rows.
//
// STORE-PATTERN CHANGE (this round's single variable):
//  - lane owns a float4 p-chunk: p = 4*(lane&31) .. +3
//  - half-wave h = lane>>5 owns j-row parity; one store instruction writes
//    TWO adjacent j rows = 64 lanes x 16 B = 1 KB contiguous, PLAIN store
//    (no nontemporal) — exactly the pattern that measures 6.3 TB/s on this
//    chip (m13 float4 copy / the harness fill). Rounds 1-3 used 8 B/lane
//    nontemporal stores and were pinned at ~2.4 TB/s regardless of schedule.
//  - kw4[c] = k[i,c] * W1[c, p-chunk] lives in 128 VGPRs; q + Aq double-
//    buffered, prefetch issued before the store (keeps loads older than
//    stores in the in-order vmcnt queue).
// Tail prefetches read a few rows past qk/Aq ends — lands inside the
// contiguous 1.25 MB workspace, values unused.
// ---------------------------------------------------------------------------
__global__ __launch_bounds__(256, 2) void pair_kernel(
    const float* __restrict__ qk,   // (1024, 64)
    const float* __restrict__ Aq,   // (1024, 128)
    const float* __restrict__ Ak,   // (1024, 128)
    const float* __restrict__ ow,   // (64, 128); W1 = rows 0..31
    const float* __restrict__ ob,   // (128)
    float* __restrict__ out)        // (1024, 1024, 128)
{
    const int i    = blockIdx.x;
    const int jblk = blockIdx.y;
    const int lane = threadIdx.x & 63;
    const int wv   = threadIdx.x >> 6;
    const int h    = lane >> 5;      // j-row parity owned by this half-wave
    const int pl   = lane & 31;      // float4 p-chunk index

    // kw4[c] = k[i,c] * W1[c, 4*pl .. 4*pl+3]   (128 VGPRs)
    f4 kw4[32];
    {
        const float4* kvp = (const float4*)(qk + (size_t)i * 64 + 32);
        #pragma unroll
        for (int c4 = 0; c4 < 8; ++c4) {
            float4 kv = kvp[c4];
            const f4* wa = (const f4*)(ow + (size_t)(c4*4+0) * PAIR) + pl;
            const f4* wb = (const f4*)(ow + (size_t)(c4*4+1) * PAIR) + pl;
            const f4* wc = (const f4*)(ow + (size_t)(c4*4+2) * PAIR) + pl;
            const f4* wd = (const f4*)(ow + (size_t)(c4*4+3) * PAIR) + pl;
            kw4[c4*4+0] = kv.x * wa[0];
            kw4[c4*4+1] = kv.y * wb[0];
            kw4[c4*4+2] = kv.z * wc[0];
            kw4[c4*4+3] = kv.w * wd[0];
        }
    }

    const f4 bias = ((const f4*)ob)[pl] - ((const f4*)(Ak + (size_t)i * PAIR))[pl];

    const int j0 = __builtin_amdgcn_readfirstlane(jblk * 128 + wv * 32);

    // stage t (t=0..15) handles row r = j0 + 2t + h
    const f4* qp  = (const f4*)(qk + (size_t)(j0 + h) * 64);           // q row: qp[t*32 + c4]
    const f4* aqp = (const f4*)Aq + ((size_t)(j0 + h) * 32 + pl);      // Aq:    aqp[t*64]
    f4*       op  = (f4*)out + (((size_t)i * LSEQ + (j0 + h)) * 32 + pl); // out: op[t*64]

    f4 qA[8], qB[8], aqA, aqB;
    #pragma unroll
    for (int c4 = 0; c4 < 8; ++c4) qA[c4] = qp[c4];
    aqA = aqp[0];
    #pragma unroll
    for (int c4 = 0; c4 < 8; ++c4) qB[c4] = qp[32 + c4];
    aqB = aqp[64];

    #pragma unroll 1
    for (int t = 0; t < 16; t += 2) {
        // ---- even stage: row j0 + 2t + h, consumes qA/aqA ----
        {
            f4 acc0 = bias + aqA;
            f4 acc1 = {0.f, 0.f, 0.f, 0.f};
            #pragma unroll
            for (int c4 = 0; c4 < 4; ++c4) {
                f4 qv = qA[c4];
                f4 qw = qA[c4 + 4];
                acc0 += qv.x * kw4[c4*4+0];   acc1 += qw.x * kw4[16 + c4*4+0];
                acc0 += qv.y * kw4[c4*4+1];   acc1 += qw.y * kw4[16 + c4*4+1];
                acc0 += qv.z * kw4[c4*4+2];   acc1 += qw.z * kw4[16 + c4*4+2];
                acc0 += qv.w * kw4[c4*4+3];   acc1 += qw.w * kw4[16 + c4*4+3];
            }
            // prefetch stage t+2 BEFORE the store
            #pragma unroll
            for (int c4 = 0; c4 < 8; ++c4) qA[c4] = qp[(size_t)(t + 2) * 32 + c4];
            aqA = aqp[(size_t)(t + 2) * 64];
            op[(size_t)t * 64] = acc0 + acc1;          // plain dwordx4 store
        }
        // ---- odd stage: row j0 + 2t + 2 + h, consumes qB/aqB ----
        {
            f4 acc0 = bias + aqB;
            f4 acc1 = {0.f, 0.f, 0.f, 0.f};
            #pragma unroll
            for (int c4 = 0; c4 < 4; ++c4) {
                f4 qv = qB[c4];
                f4 qw = qB[c4 + 4];
                acc0 += qv.x * kw4[c4*4+0];   acc1 += qw.x * kw4[16 + c4*4+0];
                acc0 += qv.y * kw4[c4*4+1];   acc1 += qw.y * kw4[16 + c4*4+1];
                acc0 += qv.z * kw4[c4*4+2];   acc1 += qw.z * kw4[16 + c4*4+2];
                acc0 += qv.w * kw4[c4*4+3];   acc1 += qw.w * kw4[16 + c4*4+3];
            }
            // prefetch stage t+3 BEFORE the store
            #pragma unroll
            for (int c4 = 0; c4 < 8; ++c4) qB[c4] = qp[(size_t)(t + 3) * 32 + c4];
            aqB = aqp[(size_t)(t + 3) * 64];
            op[(size_t)(t + 1) * 64] = acc0 + acc1;    // plain dwordx4 store
        }
    }
}

extern "C" void kernel_launch(void* const* d_in, const int* in_sizes, int n_in,
                              void* d_out, int out_size, void* d_ws, size_t ws_size,
                              hipStream_t stream) {
    const float* x     = (const float*)d_in[0];
    const float* gamma = (const float*)d_in[1];
    const float* beta  = (const float*)d_in[2];
    const float* pw    = (const float*)d_in[3];
    const float* pb    = (const float*)d_in[4];
    const float* ow    = (const float*)d_in[5];
    const float* ob    = (const float*)d_in[6];
    float* out = (float*)d_out;

    // workspace layout
    float* qk = (float*)d_ws;                 // 1024*64  = 256 KB
    float* Aq = qk + (size_t)LSEQ * 64;       // 1024*128 = 512 KB
    float* Ak = Aq + (size_t)LSEQ * PAIR;     // 1024*128 = 512 KB

    ln_proj_kernel<<<dim3(LSEQ), dim3(256), 0, stream>>>(
        x, gamma, beta, pw, pb, ow, qk, Aq, Ak);

    pair_kernel<<<dim3(LSEQ, 8), dim3(256), 0, stream>>>(
        qk, Aq, Ak, ow, ob, out);
}